// Round 7
// baseline (133.782 us; speedup 1.0000x reference)
//
#include <hip/hip_runtime.h>
#include <hip/hip_bf16.h>

// Problem constants (Whisper-style MHA): B=2, S=2048, D=1024, H=16, hd=64
#define BB 2
#define SS 2048
#define DD 1024
#define HH 16
#define HD 64
#define QKSCALE 0.35355339059327373f   // 64^-0.25
// 64^-0.25 * sqrt(log2(e)) : folds exp->exp2 domain change into q,k projections
#define QKSCALE_E2 0.42466090144f
#define NEGBIG (-1e9f)

using u16 = unsigned short;
typedef __attribute__((ext_vector_type(8))) short short8;     // 8 bf16 = 4 VGPR
typedef __attribute__((ext_vector_type(4))) float floatx4;    // MFMA acc
typedef __attribute__((ext_vector_type(4))) unsigned short ushort4v;

#define GLOBAL_AS __attribute__((address_space(1)))
#define LDS_AS __attribute__((address_space(3)))

__device__ __forceinline__ u16 f2b(float f) {          // RNE f32->bf16
  union { float f; unsigned u; } v; v.f = f;
  return (u16)((v.u + 0x7fffu + ((v.u >> 16) & 1u)) >> 16);
}

__device__ __forceinline__ u16 bconv(float f) {        // via HW cvt (fuses to cvt_pk)
  union { __hip_bfloat16 h; u16 u; } cv;
  cv.h = __float2bfloat16(f);
  return cv.u;
}

__device__ __forceinline__ float ex2(float f) {        // raw v_exp_f32 (2^x)
  return __builtin_amdgcn_exp2f(f);
}

__device__ __forceinline__ floatx4 vmax4(floatx4 a, floatx4 b) {
  return (floatx4){fmaxf(a[0], b[0]), fmaxf(a[1], b[1]),
                   fmaxf(a[2], b[2]), fmaxf(a[3], b[3])};
}

__device__ __forceinline__ void gload_lds16(const void* g, void* l) {
  __builtin_amdgcn_global_load_lds((GLOBAL_AS void*)(g), (LDS_AS void*)(l), 16, 0, 0);
}

// ---------------- elementwise f32 -> bf16 ----------------
__global__ __launch_bounds__(256) void cvt_bf16x4(const float4* __restrict__ src,
                                                  ushort4v* __restrict__ dst, int n4) {
  int i = blockIdx.x * 256 + threadIdx.x;
  if (i >= n4) return;
  float4 f = src[i];
  ushort4v o = { f2b(f.x), f2b(f.y), f2b(f.z), f2b(f.w) };
  dst[i] = o;
}

// ------------- weight transpose+convert: W[K][N] f32 -> Wt[N][K] bf16 (4 weights) -------------
__global__ __launch_bounds__(256) void transpose_w(const float* __restrict__ s0,
                                                   const float* __restrict__ s1,
                                                   const float* __restrict__ s2,
                                                   const float* __restrict__ s3,
                                                   u16* __restrict__ dst) {
  __shared__ float tile[32][33];
  const float* src = (blockIdx.z == 0) ? s0 : (blockIdx.z == 1) ? s1
                   : (blockIdx.z == 2) ? s2 : s3;
  u16* d = dst + (size_t)blockIdx.z * 1024 * 1024;
  int c0 = blockIdx.x * 32, r0 = blockIdx.y * 32;
  int tx = threadIdx.x, ty = threadIdx.y;     // block (32,8)
#pragma unroll
  for (int i = 0; i < 4; ++i)
    tile[ty + i * 8][tx] = src[(size_t)(r0 + ty + i * 8) * 1024 + c0 + tx];
  __syncthreads();
#pragma unroll
  for (int i = 0; i < 4; ++i)
    d[(size_t)(c0 + ty + i * 8) * 1024 + r0 + tx] = f2b(tile[tx][ty + i * 8]);
}

// ------------- V [B*S][D] bf16 -> Vt [B*D][S] bf16 (per-batch transpose) -------------
__global__ __launch_bounds__(256) void transpose_v(const u16* __restrict__ v,
                                                   u16* __restrict__ vtd) {
  __shared__ u16 tile[32][34];
  int b = blockIdx.z;
  int c0 = blockIdx.x * 32;   // d
  int s0 = blockIdx.y * 32;   // s
  int tx = threadIdx.x, ty = threadIdx.y;
#pragma unroll
  for (int i = 0; i < 4; ++i)
    tile[ty + i * 8][tx] = v[(size_t)(b * SS + s0 + ty + i * 8) * DD + c0 + tx];
  __syncthreads();
#pragma unroll
  for (int i = 0; i < 4; ++i)
    vtd[(size_t)(b * DD + c0 + ty + i * 8) * SS + s0 + tx] = tile[tx][ty + i * 8];
}

// ------------- GEMM (2-barrier 128^2, used for out-proj): C = A @ Bt^T -------------
template <typename OutT>
__global__ __launch_bounds__(256)
void gemm_bt(const u16* __restrict__ A, const u16* __restrict__ Bt,
             OutT* __restrict__ C, const float* __restrict__ bias,
             float scale, int M, int N, int K) {
  const int tid = threadIdx.x;
  const int lane = tid & 63;
  const int w = tid >> 6;
  const int m0 = blockIdx.x * 128;
  const int n0 = blockIdx.y * 128;
  __shared__ u16 As[128 * 64];
  __shared__ u16 Bs[128 * 64];
  floatx4 acc[4][4];
#pragma unroll
  for (int i = 0; i < 4; ++i)
#pragma unroll
    for (int j = 0; j < 4; ++j) acc[i][j] = (floatx4){0.f, 0.f, 0.f, 0.f};

  const int wr = (w >> 1) * 64;
  const int wc = (w & 1) * 64;
  const int g = lane >> 4;
  const int lr = lane & 15;
  const size_t strideA = (size_t)K * 2;

  for (int k0 = 0; k0 < K; k0 += 64) {
#pragma unroll
    for (int p = 0; p < 4; ++p) {
      int L = tid * 16 + p * 4096;
      int row = L >> 7;
      int cb = (L ^ ((row & 7) << 4)) & 127;
      gload_lds16((const char*)A + (size_t)(m0 + row) * strideA + k0 * 2 + cb,
                  (char*)As + p * 4096 + w * 1024);
      gload_lds16((const char*)Bt + (size_t)(n0 + row) * strideA + k0 * 2 + cb,
                  (char*)Bs + p * 4096 + w * 1024);
    }
    __syncthreads();
#pragma unroll
    for (int ks = 0; ks < 2; ++ks) {
      short8 af[4], bf[4];
      const int c0 = ks * 32 + g * 8;
#pragma unroll
      for (int mi = 0; mi < 4; ++mi) {
        int row = wr + mi * 16 + lr;
        af[mi] = *(const short8*)(As + row * 64 + (c0 ^ ((row & 7) << 3)));
      }
#pragma unroll
      for (int ni = 0; ni < 4; ++ni) {
        int row = wc + ni * 16 + lr;
        bf[ni] = *(const short8*)(Bs + row * 64 + (c0 ^ ((row & 7) << 3)));
      }
#pragma unroll
      for (int mi = 0; mi < 4; ++mi)
#pragma unroll
        for (int ni = 0; ni < 4; ++ni)
          acc[mi][ni] = __builtin_amdgcn_mfma_f32_16x16x32_bf16(af[mi], bf[ni],
                                                                acc[mi][ni], 0, 0, 0);
    }
    __syncthreads();
  }
#pragma unroll
  for (int ni = 0; ni < 4; ++ni) {
    int col = n0 + wc + ni * 16 + lr;
    float bvv = bias ? bias[col] : 0.f;
#pragma unroll
    for (int mi = 0; mi < 4; ++mi) {
#pragma unroll
      for (int r = 0; r < 4; ++r) {
        int rowg = m0 + wr + mi * 16 + g * 4 + r;
        float val = (acc[mi][ni][r] + bvv) * scale;
        if constexpr (sizeof(OutT) == 4) C[(size_t)rowg * N + col] = val;
        else C[(size_t)rowg * N + col] = (OutT)f2b(val);
      }
    }
  }
}

// ============ fused QKV GEMM: 256x256 tile, BK=64, 8 waves, 8-phase counted-vmcnt ============
// C[4096][3072] = xb @ [Wq^T|Wk^T|Wv^T]^T, epilogue bias+scale -> bf16 into q|k|v slabs.
// Phase q of tile kt computes C-quadrant (mh=q>>1, nh=q&1) over full K=64, reading only
// A-half(mh) + B-half(nh). Staging schedule (half staged one phase AFTER its last reader's
// barrier -> provably race-free):
//   q0: stage (kt+1).A1   q1: stage (kt+1).B1   q2: stage (kt+2).A0   q3: stage (kt+2).B0
// Every staged half has >=4 phases before first use -> uniform vmcnt(6) (3 halves in flight).
template <int Q>
__device__ __forceinline__ void qkv_phase_core(
    const u16* __restrict__ Ah, const u16* __restrict__ Bh,
    floatx4 (&acc)[4][4][2], int wsr, int wsc, int g, int lr) {
  short8 af[4][2], bfv[2][2];
#pragma unroll
  for (int mi = 0; mi < 4; ++mi) {
    int row = wsr * 64 + mi * 16 + lr;
    int sw = (row & 7) << 4;
#pragma unroll
    for (int ks = 0; ks < 2; ++ks)
      af[mi][ks] = *(const short8*)((const char*)Ah + row * 128 + ((ks * 64 + g * 16) ^ sw));
  }
#pragma unroll
  for (int ni = 0; ni < 2; ++ni) {
    int row = wsc * 32 + ni * 16 + lr;
    int sw = (row & 7) << 4;
#pragma unroll
    for (int ks = 0; ks < 2; ++ks)
      bfv[ni][ks] = *(const short8*)((const char*)Bh + row * 128 + ((ks * 64 + g * 16) ^ sw));
  }
  __builtin_amdgcn_s_setprio(1);
#pragma unroll
  for (int mi = 0; mi < 4; ++mi)
#pragma unroll
    for (int ni = 0; ni < 2; ++ni)
#pragma unroll
      for (int ks = 0; ks < 2; ++ks)
        acc[Q][mi][ni] = __builtin_amdgcn_mfma_f32_16x16x32_bf16(
            af[mi][ks], bfv[ni][ks], acc[Q][mi][ni], 0, 0, 0);
  __builtin_amdgcn_s_setprio(0);
}

#define PH_WAIT(N)                                         \
  do {                                                     \
    asm volatile("s_waitcnt vmcnt(" #N ")" ::: "memory");  \
    __builtin_amdgcn_s_barrier();                          \
    __builtin_amdgcn_sched_barrier(0);                     \
  } while (0)

__global__ __launch_bounds__(512, 2)
void gemm_qkv8(const u16* __restrict__ A, const u16* __restrict__ Wt3,
               u16* __restrict__ Out3, const float* __restrict__ bq,
               const float* __restrict__ bv) {
  const int tid = threadIdx.x;
  const int lane = tid & 63;
  const int w = tid >> 6;          // 0..7
  const int g = lane >> 4;
  const int lr = lane & 15;
  const int wsr = w >> 2;          // 0..1 : 64-row sub within quadrant
  const int wsc = w & 3;           // 0..3 : 32-col sub within quadrant
  // bijective XCD swizzle (192 % 8 == 0): 24 consecutive per XCD, B-panel reuse
  const int id = (int)blockIdx.x;
  const int swz = (id & 7) * 24 + (id >> 3);
  const int m0 = (swz & 15) * 256;
  const int n0 = (swz >> 4) * 256;

  __shared__ u16 Alds[2][2][128 * 64];   // [buf][half][128 rows x 64 cols] = 64KB
  __shared__ u16 Blds[2][2][128 * 64];   // 64KB

  const char* asrc = (const char*)A + (size_t)m0 * 2048;
  const char* bsrc = (const char*)Wt3 + (size_t)n0 * 2048;

  auto stage = [&](int mat, int kt, int half, int buf) {
    const char* src = (mat == 0) ? asrc : bsrc;
    char* dst = (char*)((mat == 0) ? &Alds[buf][half][0] : &Blds[buf][half][0]) + w * 1024;
#pragma unroll
    for (int j = 0; j < 2; ++j) {
      int L = tid * 16 + j * 8192;
      int row = L >> 7;
      int cb = (L ^ ((row & 7) << 4)) & 127;   // inverse-swizzled source col
      gload_lds16(src + (size_t)(half * 128 + row) * 2048 + kt * 128 + cb,
                  dst + j * 8192);
    }
  };

  floatx4 acc[4][4][2];
#pragma unroll
  for (int q = 0; q < 4; ++q)
#pragma unroll
    for (int mi = 0; mi < 4; ++mi)
#pragma unroll
      for (int ni = 0; ni < 2; ++ni) acc[q][mi][ni] = (floatx4){0.f, 0.f, 0.f, 0.f};

  // prologue: t0 all 4 halves + t1.A0, t1.B0  (6 halves, 12 loads in flight)
  stage(0, 0, 0, 0); stage(1, 0, 0, 0);
  stage(0, 0, 1, 0); stage(1, 0, 1, 0);
  stage(0, 1, 0, 1); stage(1, 1, 0, 1);

  for (int kt = 0; kt < 15; ++kt) {
    const int buf = kt & 1, nbuf = buf ^ 1;
    PH_WAIT(6);
    stage(0, kt + 1, 1, nbuf);                       // (kt+1).A1
    qkv_phase_core<0>(Alds[buf][0], Blds[buf][0], acc, wsr, wsc, g, lr);
    PH_WAIT(6);
    stage(1, kt + 1, 1, nbuf);                       // (kt+1).B1
    qkv_phase_core<1>(Alds[buf][0], Blds[buf][1], acc, wsr, wsc, g, lr);
    PH_WAIT(6);
    if (kt < 14) stage(0, kt + 2, 0, buf);           // (kt+2).A0
    qkv_phase_core<2>(Alds[buf][1], Blds[buf][0], acc, wsr, wsc, g, lr);
    PH_WAIT(6);
    if (kt < 14) stage(1, kt + 2, 0, buf);           // (kt+2).B0
    qkv_phase_core<3>(Alds[buf][1], Blds[buf][1], acc, wsr, wsc, g, lr);
  }
  // kt = 15 peeled: no staging, drain 4 -> 0
  {
    PH_WAIT(4);
    qkv_phase_core<0>(Alds[1][0], Blds[1][0], acc, wsr, wsc, g, lr);
    PH_WAIT(0);
    qkv_phase_core<1>(Alds[1][0], Blds[1][1], acc, wsr, wsc, g, lr);
    __builtin_amdgcn_s_barrier();
    qkv_phase_core<2>(Alds[1][1], Blds[1][0], acc, wsr, wsc, g, lr);
    __builtin_amdgcn_s_barrier();
    qkv_phase_core<3>(Alds[1][1], Blds[1][1], acc, wsr, wsc, g, lr);
  }

  // epilogue: (acc + bias) * scale -> bf16 into the q/k/v slab
  const int seg = n0 >> 10;                   // block fully inside one segment
  const float scale = (seg == 2) ? 1.0f : QKSCALE_E2;
  const float* bias = (seg == 0) ? bq : (seg == 2) ? bv : nullptr;
  u16* outBase = Out3 + (size_t)seg * 4096 * 1024;
  const int nnBase = n0 & 1023;
#pragma unroll
  for (int q = 0; q < 4; ++q) {
    const int rq = (q >> 1) * 128, cq = (q & 1) * 128;
#pragma unroll
    for (int ni = 0; ni < 2; ++ni) {
      int colInB = cq + wsc * 32 + ni * 16 + lr;
      float bvv = bias ? bias[nnBase + colInB] : 0.f;
#pragma unroll
      for (int mi = 0; mi < 4; ++mi) {
#pragma unroll
        for (int r = 0; r < 4; ++r) {
          int rowg = m0 + rq + wsr * 64 + mi * 16 + g * 4 + r;
          outBase[(size_t)rowg * 1024 + nnBase + colInB] =
              f2b((acc[q][mi][ni][r] + bvv) * scale);
        }
      }
    }
  }
}

// ------------- flash attention: swapped-QK (S^T), single stream, 1 q-tile/block -------------
__device__ __forceinline__ void stream_softmax(floatx4 (&sa)[4], float& m, float& l,
                                               floatx4 (&acc)[4], u16* pl,
                                               bool diag, int wlr, int g, int lr) {
  if (diag) {
#pragma unroll
    for (int ct = 0; ct < 4; ++ct)
#pragma unroll
      for (int r = 0; r < 4; ++r)
        if (ct * 16 + g * 4 + r > wlr) sa[ct][r] += NEGBIG;
  }
  floatx4 v = vmax4(vmax4(sa[0], sa[1]), vmax4(sa[2], sa[3]));
  float mx = fmaxf(fmaxf(v[0], v[1]), fmaxf(v[2], v[3]));
  mx = fmaxf(mx, __shfl_xor(mx, 16, 64));
  mx = fmaxf(mx, __shfl_xor(mx, 32, 64));
  if (!__all(mx <= m + 8.f)) {
    float mn = fmaxf(m, mx);
    float al = ex2(m - mn);
    l *= al;
#pragma unroll
    for (int dt = 0; dt < 4; ++dt) acc[dt] *= al;
    m = mn;
  }
  floatx4 p[4];
#pragma unroll
  for (int ct = 0; ct < 4; ++ct)
#pragma unroll
    for (int r = 0; r < 4; ++r)
      p[ct][r] = ex2(sa[ct][r] - m);
  floatx4 s = (p[0] + p[1]) + (p[2] + p[3]);
  float rs = (s[0] + s[1]) + (s[2] + s[3]);
  rs += __shfl_xor(rs, 16, 64);
  rs += __shfl_xor(rs, 32, 64);
  l += rs;
#pragma unroll
  for (int ct = 0; ct < 4; ++ct) {
    ushort4v pk = { bconv(p[ct][0]), bconv(p[ct][1]),
                    bconv(p[ct][2]), bconv(p[ct][3]) };
    *(ushort4v*)((char*)pl + ((lr * 128 + ct * 32 + g * 8) ^ ((lr & 7) << 4))) = pk;
  }
}

__global__ __launch_bounds__(256, 4)
void flash_attn(const u16* __restrict__ q, const u16* __restrict__ k,
                const u16* __restrict__ vt, u16* __restrict__ o) {
  const int tid = threadIdx.x;
  const int lane = tid & 63;
  const int w = tid >> 6;
  const int g = lane >> 4;
  const int lr = lane & 15;
  const int i = (int)blockIdx.x;      // 0..1023
  const int x = i & 7;
  const int kk = i >> 3;
  const int c = kk & 31;
  const int quarter = kk >> 5;
  const int gg = x + 8 * quarter;
  const int b = gg >> 4;
  const int h = gg & 15;
  int qt;
  if (quarter == 0) qt = 31 - c;
  else if (quarter == 1) qt = c;
  else if (quarter == 2) qt = (47 - c) & 31;
  else qt = (c + 16) & 31;
  const int row0 = qt * 64 + w * 16;
  const int wlr = w * 16 + lr;

  __shared__ u16 Ks[2][64 * 64];
  __shared__ u16 Vs[2][64 * 64];
  __shared__ u16 Pl[4][16 * 64];

  short8 qf[2];
  {
    const u16* qp = q + (size_t)(b * SS + row0 + lr) * DD + h * HD + g * 8;
    qf[0] = *(const short8*)qp;
    qf[1] = *(const short8*)(qp + 32);
  }
  floatx4 acc[4];
#pragma unroll
  for (int dt = 0; dt < 4; ++dt) acc[dt] = (floatx4){0.f, 0.f, 0.f, 0.f};
  float m = -1e30f, l = 0.f;

  const char* kbase = (const char*)(k + (size_t)(b * SS) * DD + h * HD);
  const char* vbase = (const char*)(vt + (size_t)((b * HH + h) * HD) * SS);
  const int nt = qt + 1;

  auto stage = [&](int t, int buf) {
    const int kvb = t * 64;
#pragma unroll
    for (int p = 0; p < 2; ++p) {
      int L = tid * 16 + p * 4096;
      int row = L >> 7;
      int cb = (L ^ ((row & 7) << 4)) & 127;
      gload_lds16(kbase + (size_t)(kvb + row) * (DD * 2) + cb,
                  (char*)Ks + buf * 8192 + p * 4096 + w * 1024);
      gload_lds16(vbase + (size_t)row * (SS * 2) + kvb * 2 + cb,
                  (char*)Vs + buf * 8192 + p * 4096 + w * 1024);
    }
  };

  stage(0, 0);
  int cur = 0;
  for (int t = 0; t < nt; ++t) {
    __syncthreads();
    if (t + 1 < nt) stage(t + 1, cur ^ 1);
    const u16* kc = Ks[cur];
    const u16* vc = Vs[cur];

    floatx4 sa[4];
#pragma unroll
    for (int ct = 0; ct < 4; ++ct) sa[ct] = (floatx4){0.f, 0.f, 0.f, 0.f};
    __builtin_amdgcn_s_setprio(1);
#pragma unroll
    for (int ks = 0; ks < 2; ++ks) {
      const int c0 = ks * 32 + g * 8;
#pragma unroll
      for (int ct = 0; ct < 4; ++ct) {
        int row = ct * 16 + lr;
        short8 kf = *(const short8*)(kc + row * 64 + (c0 ^ ((row & 7) << 3)));
        sa[ct] = __builtin_amdgcn_mfma_f32_16x16x32_bf16(kf, qf[ks], sa[ct], 0, 0, 0);
      }
    }
    __builtin_amdgcn_s_setprio(0);

    stream_softmax(sa, m, l, acc, Pl[w], t == qt, wlr, g, lr);
    asm volatile("" ::: "memory");

    __builtin_amdgcn_s_setprio(1);
#pragma unroll
    for (int ks = 0; ks < 2; ++ks) {
      const int c0 = ks * 32 + g * 8;
      int pby = (lr * 128 + ks * 64 + g * 16) ^ ((lr & 7) << 4);
      short8 pf = *(const short8*)((const char*)Pl[w] + pby);
#pragma unroll
      for (int dt = 0; dt < 4; ++dt) {
        int row = dt * 16 + lr;
        short8 vf = *(const short8*)(vc + row * 64 + (c0 ^ ((row & 7) << 3)));
        acc[dt] = __builtin_amdgcn_mfma_f32_16x16x32_bf16(vf, pf, acc[dt], 0, 0, 0);
      }
    }
    __builtin_amdgcn_s_setprio(0);
    asm volatile("" ::: "memory");
    cur ^= 1;
  }

  float inv = 1.0f / l;
#pragma unroll
  for (int dt = 0; dt < 4; ++dt) {
    ushort4v pa = { bconv(acc[dt][0] * inv), bconv(acc[dt][1] * inv),
                    bconv(acc[dt][2] * inv), bconv(acc[dt][3] * inv) };
    *(ushort4v*)(o + (size_t)(b * SS + row0 + lr) * DD + h * HD + dt * 16 + g * 4) = pa;
  }
}

extern "C" void kernel_launch(void* const* d_in, const int* in_sizes, int n_in,
                              void* d_out, int out_size, void* d_ws, size_t ws_size,
                              hipStream_t stream) {
  const float* x  = (const float*)d_in[0];
  // d_in[1] = mask: causal additive -1e9, replicated analytically in-kernel
  const float* Wq = (const float*)d_in[2];
  const float* bq = (const float*)d_in[3];
  const float* Wk = (const float*)d_in[4];
  const float* Wv = (const float*)d_in[5];
  const float* bv = (const float*)d_in[6];
  const float* Wo = (const float*)d_in[7];
  const float* bo = (const float*)d_in[8];
  float* out = (float*)d_out;

  char* ws = (char*)d_ws;
  u16* xb  = (u16*)(ws);                    // 8MB  x bf16 [4096][1024]
  u16* wt  = (u16*)(ws + (8u << 20));       // 8MB  Wq^T,Wk^T,Wv^T,Wo^T bf16
  u16* qkv = (u16*)(ws + (16u << 20));      // 24MB q,k,v bf16 [4096][1024] each
  u16* vb  = qkv + 2u * 4096 * 1024;
  u16* vtb = (u16*)(ws + (40u << 20));      // 8MB  v^T per batch [B*D][S]
  u16* ob  = (u16*)(ws + (48u << 20));      // 8MB  attn out bf16
  u16* wot = wt + 3u * 1024 * 1024;

  dim3 tb(32, 8);
  cvt_bf16x4<<<4096, 256, 0, stream>>>((const float4*)x, (ushort4v*)xb,
                                       (BB * SS * DD) / 4);
  transpose_w<<<dim3(32, 32, 4), tb, 0, stream>>>(Wq, Wk, Wv, Wo, wt);
  gemm_qkv8<<<192, 512, 0, stream>>>(xb, wt, qkv, bq, bv);
  transpose_v<<<dim3(32, 64, 2), tb, 0, stream>>>(vb, vtb);
  flash_attn<<<1024, 256, 0, stream>>>(qkv, qkv + (size_t)4096 * 1024, vtb, ob);
  gemm_bt<float><<<dim3(32, 8), 256, 0, stream>>>(ob, wot, out, bo, 1.0f,
                                                  4096, 1024, 1024);
}

// Round 8
// 121.645 us; speedup vs baseline: 1.0998x; 1.0998x over previous
//
#include <hip/hip_runtime.h>
#include <hip/hip_bf16.h>

// Problem constants (Whisper-style MHA): B=2, S=2048, D=1024, H=16, hd=64
#define BB 2
#define SS 2048
#define DD 1024
#define HH 16
#define HD 64
#define QKSCALE 0.35355339059327373f   // 64^-0.25
// 64^-0.25 * sqrt(log2(e)) : folds exp->exp2 domain change into q,k projections
#define QKSCALE_E2 0.42466090144f
#define NEGBIG (-1e9f)

using u16 = unsigned short;
typedef __attribute__((ext_vector_type(8))) short short8;     // 8 bf16 = 4 VGPR
typedef __attribute__((ext_vector_type(4))) float floatx4;    // MFMA acc
typedef __attribute__((ext_vector_type(4))) unsigned short ushort4v;

#define GLOBAL_AS __attribute__((address_space(1)))
#define LDS_AS __attribute__((address_space(3)))

__device__ __forceinline__ u16 f2b(float f) {          // RNE f32->bf16
  union { float f; unsigned u; } v; v.f = f;
  return (u16)((v.u + 0x7fffu + ((v.u >> 16) & 1u)) >> 16);
}

__device__ __forceinline__ u16 bconv(float f) {        // via HW cvt (fuses to cvt_pk)
  union { __hip_bfloat16 h; u16 u; } cv;
  cv.h = __float2bfloat16(f);
  return cv.u;
}

__device__ __forceinline__ float ex2(float f) {        // raw v_exp_f32 (2^x)
  return __builtin_amdgcn_exp2f(f);
}

__device__ __forceinline__ floatx4 vmax4(floatx4 a, floatx4 b) {
  return (floatx4){fmaxf(a[0], b[0]), fmaxf(a[1], b[1]),
                   fmaxf(a[2], b[2]), fmaxf(a[3], b[3])};
}

__device__ __forceinline__ void gload_lds16(const void* g, void* l) {
  __builtin_amdgcn_global_load_lds((GLOBAL_AS void*)(g), (LDS_AS void*)(l), 16, 0, 0);
}

// ---------------- elementwise f32 -> bf16 ----------------
__global__ __launch_bounds__(256) void cvt_bf16x4(const float4* __restrict__ src,
                                                  ushort4v* __restrict__ dst, int n4) {
  int i = blockIdx.x * 256 + threadIdx.x;
  if (i >= n4) return;
  float4 f = src[i];
  ushort4v o = { f2b(f.x), f2b(f.y), f2b(f.z), f2b(f.w) };
  dst[i] = o;
}

// ------------- weight transpose+convert: W[K][N] f32 -> Wt[N][K] bf16 (4 weights) -------------
__global__ __launch_bounds__(256) void transpose_w(const float* __restrict__ s0,
                                                   const float* __restrict__ s1,
                                                   const float* __restrict__ s2,
                                                   const float* __restrict__ s3,
                                                   u16* __restrict__ dst) {
  __shared__ float tile[32][33];
  const float* src = (blockIdx.z == 0) ? s0 : (blockIdx.z == 1) ? s1
                   : (blockIdx.z == 2) ? s2 : s3;
  u16* d = dst + (size_t)blockIdx.z * 1024 * 1024;
  int c0 = blockIdx.x * 32, r0 = blockIdx.y * 32;
  int tx = threadIdx.x, ty = threadIdx.y;     // block (32,8)
#pragma unroll
  for (int i = 0; i < 4; ++i)
    tile[ty + i * 8][tx] = src[(size_t)(r0 + ty + i * 8) * 1024 + c0 + tx];
  __syncthreads();
#pragma unroll
  for (int i = 0; i < 4; ++i)
    d[(size_t)(c0 + ty + i * 8) * 1024 + r0 + tx] = f2b(tile[tx][ty + i * 8]);
}

// ------------- V [B*S][D] bf16 -> Vt [B*D][S] bf16 (per-batch transpose) -------------
__global__ __launch_bounds__(256) void transpose_v(const u16* __restrict__ v,
                                                   u16* __restrict__ vtd) {
  __shared__ u16 tile[32][34];
  int b = blockIdx.z;
  int c0 = blockIdx.x * 32;   // d
  int s0 = blockIdx.y * 32;   // s
  int tx = threadIdx.x, ty = threadIdx.y;
#pragma unroll
  for (int i = 0; i < 4; ++i)
    tile[ty + i * 8][tx] = v[(size_t)(b * SS + s0 + ty + i * 8) * DD + c0 + tx];
  __syncthreads();
#pragma unroll
  for (int i = 0; i < 4; ++i)
    vtd[(size_t)(b * DD + c0 + ty + i * 8) * SS + s0 + tx] = tile[tx][ty + i * 8];
}

// ------------- GEMM: C[M][N] = A[M][K] @ Bt[N][K]^T, double-buffered prefetch -------------
// 128x128 tile, BK=64, 4 waves, LDS 2x32KB. One barrier per K-step:
//   sync (drains stage(t) issued a full step ago) -> issue stage(t+1) -> compute(t).
// Overwrite of buf t&1 by stage(t+2) is safe: issued after the sync that proves all
// waves finished their (lgkm-drained) reads of that buffer.
template <typename OutT>
__global__ __launch_bounds__(256, 2)
void gemm_bt(const u16* __restrict__ A, const u16* __restrict__ Bt,
             OutT* __restrict__ C, const float* __restrict__ bias,
             float scale, int M, int N, int K) {
  const int tid = threadIdx.x;
  const int lane = tid & 63;
  const int w = tid >> 6;
  const int m0 = blockIdx.x * 128;
  const int n0 = blockIdx.y * 128;
  __shared__ u16 As[2][128 * 64];
  __shared__ u16 Bs[2][128 * 64];
  floatx4 acc[4][4];
#pragma unroll
  for (int i = 0; i < 4; ++i)
#pragma unroll
    for (int j = 0; j < 4; ++j) acc[i][j] = (floatx4){0.f, 0.f, 0.f, 0.f};

  const int wr = (w >> 1) * 64;
  const int wc = (w & 1) * 64;
  const int g = lane >> 4;
  const int lr = lane & 15;
  const size_t strideA = (size_t)K * 2;

  auto stage = [&](int k0, int buf) {
#pragma unroll
    for (int p = 0; p < 4; ++p) {
      int L = tid * 16 + p * 4096;
      int row = L >> 7;
      int cb = (L ^ ((row & 7) << 4)) & 127;
      gload_lds16((const char*)A + (size_t)(m0 + row) * strideA + k0 * 2 + cb,
                  (char*)As[buf] + p * 4096 + w * 1024);
      gload_lds16((const char*)Bt + (size_t)(n0 + row) * strideA + k0 * 2 + cb,
                  (char*)Bs[buf] + p * 4096 + w * 1024);
    }
  };

  const int nsteps = K >> 6;
  stage(0, 0);
  for (int t = 0; t < nsteps; ++t) {
    const int buf = t & 1;
    __syncthreads();                       // drains stage(t); guards buf reuse
    if (t + 1 < nsteps) stage((t + 1) << 6, buf ^ 1);
    const u16* as = As[buf];
    const u16* bs = Bs[buf];
#pragma unroll
    for (int ks = 0; ks < 2; ++ks) {
      short8 af[4], bf[4];
      const int c0 = ks * 32 + g * 8;
#pragma unroll
      for (int mi = 0; mi < 4; ++mi) {
        int row = wr + mi * 16 + lr;
        af[mi] = *(const short8*)(as + row * 64 + (c0 ^ ((row & 7) << 3)));
      }
#pragma unroll
      for (int ni = 0; ni < 4; ++ni) {
        int row = wc + ni * 16 + lr;
        bf[ni] = *(const short8*)(bs + row * 64 + (c0 ^ ((row & 7) << 3)));
      }
      __builtin_amdgcn_s_setprio(1);
#pragma unroll
      for (int mi = 0; mi < 4; ++mi)
#pragma unroll
        for (int ni = 0; ni < 4; ++ni)
          acc[mi][ni] = __builtin_amdgcn_mfma_f32_16x16x32_bf16(af[mi], bf[ni],
                                                                acc[mi][ni], 0, 0, 0);
      __builtin_amdgcn_s_setprio(0);
    }
  }
#pragma unroll
  for (int ni = 0; ni < 4; ++ni) {
    int col = n0 + wc + ni * 16 + lr;
    float bvv = bias ? bias[col] : 0.f;
#pragma unroll
    for (int mi = 0; mi < 4; ++mi) {
#pragma unroll
      for (int r = 0; r < 4; ++r) {
        int rowg = m0 + wr + mi * 16 + g * 4 + r;
        float val = (acc[mi][ni][r] + bvv) * scale;
        if constexpr (sizeof(OutT) == 4) C[(size_t)rowg * N + col] = val;
        else C[(size_t)rowg * N + col] = (OutT)f2b(val);
      }
    }
  }
}

// fused QKV wrapper (same dbuf structure): blockIdx.z selects segment (0=q,1=k,2=v)
__global__ __launch_bounds__(256, 2)
void gemm_qkv(const u16* __restrict__ A, const u16* __restrict__ Wt3,
              u16* __restrict__ Out3, const float* __restrict__ bq,
              const float* __restrict__ bv) {
  const int seg = blockIdx.z;
  const u16* Bt = Wt3 + (size_t)seg * 1024 * 1024;
  u16* C = Out3 + (size_t)seg * 4096 * 1024;
  const float* bias = (seg == 0) ? bq : (seg == 2) ? bv : nullptr;
  const float scale = (seg == 2) ? 1.0f : QKSCALE_E2;   // exp2-domain fold

  const int tid = threadIdx.x;
  const int lane = tid & 63;
  const int w = tid >> 6;
  const int m0 = blockIdx.x * 128;
  const int n0 = blockIdx.y * 128;
  __shared__ u16 As[2][128 * 64];
  __shared__ u16 Bs[2][128 * 64];
  floatx4 acc[4][4];
#pragma unroll
  for (int i = 0; i < 4; ++i)
#pragma unroll
    for (int j = 0; j < 4; ++j) acc[i][j] = (floatx4){0.f, 0.f, 0.f, 0.f};
  const int wr = (w >> 1) * 64;
  const int wc = (w & 1) * 64;
  const int g = lane >> 4;
  const int lr = lane & 15;

  auto stage = [&](int k0, int buf) {
#pragma unroll
    for (int p = 0; p < 4; ++p) {
      int L = tid * 16 + p * 4096;
      int row = L >> 7;
      int cb = (L ^ ((row & 7) << 4)) & 127;
      gload_lds16((const char*)A + (size_t)(m0 + row) * 2048 + k0 * 2 + cb,
                  (char*)As[buf] + p * 4096 + w * 1024);
      gload_lds16((const char*)Bt + (size_t)(n0 + row) * 2048 + k0 * 2 + cb,
                  (char*)Bs[buf] + p * 4096 + w * 1024);
    }
  };

  stage(0, 0);
  for (int t = 0; t < 16; ++t) {
    const int buf = t & 1;
    __syncthreads();
    if (t + 1 < 16) stage((t + 1) << 6, buf ^ 1);
    const u16* as = As[buf];
    const u16* bs = Bs[buf];
#pragma unroll
    for (int ks = 0; ks < 2; ++ks) {
      short8 af[4], bf[4];
      const int c0 = ks * 32 + g * 8;
#pragma unroll
      for (int mi = 0; mi < 4; ++mi) {
        int row = wr + mi * 16 + lr;
        af[mi] = *(const short8*)(as + row * 64 + (c0 ^ ((row & 7) << 3)));
      }
#pragma unroll
      for (int ni = 0; ni < 4; ++ni) {
        int row = wc + ni * 16 + lr;
        bf[ni] = *(const short8*)(bs + row * 64 + (c0 ^ ((row & 7) << 3)));
      }
      __builtin_amdgcn_s_setprio(1);
#pragma unroll
      for (int mi = 0; mi < 4; ++mi)
#pragma unroll
        for (int ni = 0; ni < 4; ++ni)
          acc[mi][ni] = __builtin_amdgcn_mfma_f32_16x16x32_bf16(af[mi], bf[ni],
                                                                acc[mi][ni], 0, 0, 0);
      __builtin_amdgcn_s_setprio(0);
    }
  }
#pragma unroll
  for (int ni = 0; ni < 4; ++ni) {
    int col = n0 + wc + ni * 16 + lr;
    float bvv = bias ? bias[col] : 0.f;
#pragma unroll
    for (int mi = 0; mi < 4; ++mi) {
#pragma unroll
      for (int r = 0; r < 4; ++r) {
        int rowg = m0 + wr + mi * 16 + g * 4 + r;
        C[(size_t)rowg * 1024 + col] = f2b((acc[mi][ni][r] + bvv) * scale);
      }
    }
  }
}

// ------------- flash attention: swapped-QK (S^T), single stream, 1 q-tile/block -------------
__device__ __forceinline__ void stream_softmax(floatx4 (&sa)[4], float& m, float& l,
                                               floatx4 (&acc)[4], u16* pl,
                                               bool diag, int wlr, int g, int lr) {
  if (diag) {
#pragma unroll
    for (int ct = 0; ct < 4; ++ct)
#pragma unroll
      for (int r = 0; r < 4; ++r)
        if (ct * 16 + g * 4 + r > wlr) sa[ct][r] += NEGBIG;
  }
  floatx4 v = vmax4(vmax4(sa[0], sa[1]), vmax4(sa[2], sa[3]));
  float mx = fmaxf(fmaxf(v[0], v[1]), fmaxf(v[2], v[3]));
  mx = fmaxf(mx, __shfl_xor(mx, 16, 64));
  mx = fmaxf(mx, __shfl_xor(mx, 32, 64));
  if (!__all(mx <= m + 8.f)) {
    float mn = fmaxf(m, mx);
    float al = ex2(m - mn);
    l *= al;
#pragma unroll
    for (int dt = 0; dt < 4; ++dt) acc[dt] *= al;
    m = mn;
  }
  floatx4 p[4];
#pragma unroll
  for (int ct = 0; ct < 4; ++ct)
#pragma unroll
    for (int r = 0; r < 4; ++r)
      p[ct][r] = ex2(sa[ct][r] - m);
  floatx4 s = (p[0] + p[1]) + (p[2] + p[3]);
  float rs = (s[0] + s[1]) + (s[2] + s[3]);
  rs += __shfl_xor(rs, 16, 64);
  rs += __shfl_xor(rs, 32, 64);
  l += rs;
#pragma unroll
  for (int ct = 0; ct < 4; ++ct) {
    ushort4v pk = { bconv(p[ct][0]), bconv(p[ct][1]),
                    bconv(p[ct][2]), bconv(p[ct][3]) };
    *(ushort4v*)((char*)pl + ((lr * 128 + ct * 32 + g * 8) ^ ((lr & 7) << 4))) = pk;
  }
}

__global__ __launch_bounds__(256, 4)
void flash_attn(const u16* __restrict__ q, const u16* __restrict__ k,
                const u16* __restrict__ vt, u16* __restrict__ o) {
  const int tid = threadIdx.x;
  const int lane = tid & 63;
  const int w = tid >> 6;
  const int g = lane >> 4;
  const int lr = lane & 15;
  const int i = (int)blockIdx.x;      // 0..1023
  const int x = i & 7;
  const int kk = i >> 3;
  const int c = kk & 31;
  const int quarter = kk >> 5;
  const int gg = x + 8 * quarter;
  const int b = gg >> 4;
  const int h = gg & 15;
  int qt;
  if (quarter == 0) qt = 31 - c;
  else if (quarter == 1) qt = c;
  else if (quarter == 2) qt = (47 - c) & 31;
  else qt = (c + 16) & 31;
  const int row0 = qt * 64 + w * 16;
  const int wlr = w * 16 + lr;

  __shared__ u16 Ks[2][64 * 64];
  __shared__ u16 Vs[2][64 * 64];
  __shared__ u16 Pl[4][16 * 64];

  short8 qf[2];
  {
    const u16* qp = q + (size_t)(b * SS + row0 + lr) * DD + h * HD + g * 8;
    qf[0] = *(const short8*)qp;
    qf[1] = *(const short8*)(qp + 32);
  }
  floatx4 acc[4];
#pragma unroll
  for (int dt = 0; dt < 4; ++dt) acc[dt] = (floatx4){0.f, 0.f, 0.f, 0.f};
  float m = -1e30f, l = 0.f;

  const char* kbase = (const char*)(k + (size_t)(b * SS) * DD + h * HD);
  const char* vbase = (const char*)(vt + (size_t)((b * HH + h) * HD) * SS);
  const int nt = qt + 1;

  auto stage = [&](int t, int buf) {
    const int kvb = t * 64;
#pragma unroll
    for (int p = 0; p < 2; ++p) {
      int L = tid * 16 + p * 4096;
      int row = L >> 7;
      int cb = (L ^ ((row & 7) << 4)) & 127;
      gload_lds16(kbase + (size_t)(kvb + row) * (DD * 2) + cb,
                  (char*)Ks + buf * 8192 + p * 4096 + w * 1024);
      gload_lds16(vbase + (size_t)row * (SS * 2) + kvb * 2 + cb,
                  (char*)Vs + buf * 8192 + p * 4096 + w * 1024);
    }
  };

  stage(0, 0);
  int cur = 0;
  for (int t = 0; t < nt; ++t) {
    __syncthreads();
    if (t + 1 < nt) stage(t + 1, cur ^ 1);
    const u16* kc = Ks[cur];
    const u16* vc = Vs[cur];

    floatx4 sa[4];
#pragma unroll
    for (int ct = 0; ct < 4; ++ct) sa[ct] = (floatx4){0.f, 0.f, 0.f, 0.f};
    __builtin_amdgcn_s_setprio(1);
#pragma unroll
    for (int ks = 0; ks < 2; ++ks) {
      const int c0 = ks * 32 + g * 8;
#pragma unroll
      for (int ct = 0; ct < 4; ++ct) {
        int row = ct * 16 + lr;
        short8 kf = *(const short8*)(kc + row * 64 + (c0 ^ ((row & 7) << 3)));
        sa[ct] = __builtin_amdgcn_mfma_f32_16x16x32_bf16(kf, qf[ks], sa[ct], 0, 0, 0);
      }
    }
    __builtin_amdgcn_s_setprio(0);

    stream_softmax(sa, m, l, acc, Pl[w], t == qt, wlr, g, lr);
    asm volatile("" ::: "memory");

    __builtin_amdgcn_s_setprio(1);
#pragma unroll
    for (int ks = 0; ks < 2; ++ks) {
      const int c0 = ks * 32 + g * 8;
      int pby = (lr * 128 + ks * 64 + g * 16) ^ ((lr & 7) << 4);
      short8 pf = *(const short8*)((const char*)Pl[w] + pby);
#pragma unroll
      for (int dt = 0; dt < 4; ++dt) {
        int row = dt * 16 + lr;
        short8 vf = *(const short8*)(vc + row * 64 + (c0 ^ ((row & 7) << 3)));
        acc[dt] = __builtin_amdgcn_mfma_f32_16x16x32_bf16(vf, pf, acc[dt], 0, 0, 0);
      }
    }
    __builtin_amdgcn_s_setprio(0);
    asm volatile("" ::: "memory");
    cur ^= 1;
  }

  float inv = 1.0f / l;
#pragma unroll
  for (int dt = 0; dt < 4; ++dt) {
    ushort4v pa = { bconv(acc[dt][0] * inv), bconv(acc[dt][1] * inv),
                    bconv(acc[dt][2] * inv), bconv(acc[dt][3] * inv) };
    *(ushort4v*)(o + (size_t)(b * SS + row0 + lr) * DD + h * HD + dt * 16 + g * 4) = pa;
  }
}

extern "C" void kernel_launch(void* const* d_in, const int* in_sizes, int n_in,
                              void* d_out, int out_size, void* d_ws, size_t ws_size,
                              hipStream_t stream) {
  const float* x  = (const float*)d_in[0];
  // d_in[1] = mask: causal additive -1e9, replicated analytically in-kernel
  const float* Wq = (const float*)d_in[2];
  const float* bq = (const float*)d_in[3];
  const float* Wk = (const float*)d_in[4];
  const float* Wv = (const float*)d_in[5];
  const float* bv = (const float*)d_in[6];
  const float* Wo = (const float*)d_in[7];
  const float* bo = (const float*)d_in[8];
  float* out = (float*)d_out;

  char* ws = (char*)d_ws;
  u16* xb  = (u16*)(ws);                    // 8MB  x bf16 [4096][1024]
  u16* wt  = (u16*)(ws + (8u << 20));       // 8MB  Wq^T,Wk^T,Wv^T,Wo^T bf16
  u16* qkv = (u16*)(ws + (16u << 20));      // 24MB q,k,v bf16 [4096][1024] each
  u16* vb  = qkv + 2u * 4096 * 1024;
  u16* vtb = (u16*)(ws + (40u << 20));      // 8MB  v^T per batch [B*D][S]
  u16* ob  = (u16*)(ws + (48u << 20));      // 8MB  attn out bf16
  u16* wot = wt + 3u * 1024 * 1024;

  dim3 tb(32, 8);
  cvt_bf16x4<<<4096, 256, 0, stream>>>((const float4*)x, (ushort4v*)xb,
                                       (BB * SS * DD) / 4);
  transpose_w<<<dim3(32, 32, 4), tb, 0, stream>>>(Wq, Wk, Wv, Wo, wt);
  gemm_qkv<<<dim3(32, 8, 3), 256, 0, stream>>>(xb, wt, qkv, bq, bv);
  transpose_v<<<dim3(32, 64, 2), tb, 0, stream>>>(vb, vtb);
  flash_attn<<<1024, 256, 0, stream>>>(qkv, qkv + (size_t)4096 * 1024, vtb, ob);
  gemm_bt<float><<<dim3(32, 8), 256, 0, stream>>>(ob, wot, out, bo, 1.0f,
                                                  4096, 1024, 1024);
}

// Round 9
// 120.100 us; speedup vs baseline: 1.1139x; 1.0129x over previous
//
#include <hip/hip_runtime.h>
#include <hip/hip_bf16.h>

// Problem constants (Whisper-style MHA): B=2, S=2048, D=1024, H=16, hd=64
#define BB 2
#define SS 2048
#define DD 1024
#define HH 16
#define HD 64
#define QKSCALE 0.35355339059327373f   // 64^-0.25
// 64^-0.25 * sqrt(log2(e)) : folds exp->exp2 domain change into q,k projections
#define QKSCALE_E2 0.42466090144f
#define NEGBIG (-1e9f)

using u16 = unsigned short;
typedef __attribute__((ext_vector_type(8))) short short8;     // 8 bf16 = 4 VGPR
typedef __attribute__((ext_vector_type(4))) float floatx4;    // MFMA acc
typedef __attribute__((ext_vector_type(4))) unsigned short ushort4v;

#define GLOBAL_AS __attribute__((address_space(1)))
#define LDS_AS __attribute__((address_space(3)))

__device__ __forceinline__ u16 f2b(float f) {          // RNE f32->bf16
  union { float f; unsigned u; } v; v.f = f;
  return (u16)((v.u + 0x7fffu + ((v.u >> 16) & 1u)) >> 16);
}

__device__ __forceinline__ u16 bconv(float f) {        // via HW cvt (fuses to cvt_pk)
  union { __hip_bfloat16 h; u16 u; } cv;
  cv.h = __float2bfloat16(f);
  return cv.u;
}

__device__ __forceinline__ float ex2(float f) {        // raw v_exp_f32 (2^x)
  return __builtin_amdgcn_exp2f(f);
}

__device__ __forceinline__ floatx4 vmax4(floatx4 a, floatx4 b) {
  return (floatx4){fmaxf(a[0], b[0]), fmaxf(a[1], b[1]),
                   fmaxf(a[2], b[2]), fmaxf(a[3], b[3])};
}

__device__ __forceinline__ void gload_lds16(const void* g, void* l) {
  __builtin_amdgcn_global_load_lds((GLOBAL_AS void*)(g), (LDS_AS void*)(l), 16, 0, 0);
}

// ---------------- elementwise f32 -> bf16 ----------------
__global__ __launch_bounds__(256) void cvt_bf16x4(const float4* __restrict__ src,
                                                  ushort4v* __restrict__ dst, int n4) {
  int i = blockIdx.x * 256 + threadIdx.x;
  if (i >= n4) return;
  float4 f = src[i];
  ushort4v o = { f2b(f.x), f2b(f.y), f2b(f.z), f2b(f.w) };
  dst[i] = o;
}

// ------------- weight transpose+convert: W[K][N] f32 -> Wt[N][K] bf16 (4 weights) -------------
__global__ __launch_bounds__(256) void transpose_w(const float* __restrict__ s0,
                                                   const float* __restrict__ s1,
                                                   const float* __restrict__ s2,
                                                   const float* __restrict__ s3,
                                                   u16* __restrict__ dst) {
  __shared__ float tile[32][33];
  const float* src = (blockIdx.z == 0) ? s0 : (blockIdx.z == 1) ? s1
                   : (blockIdx.z == 2) ? s2 : s3;
  u16* d = dst + (size_t)blockIdx.z * 1024 * 1024;
  int c0 = blockIdx.x * 32, r0 = blockIdx.y * 32;
  int tx = threadIdx.x, ty = threadIdx.y;     // block (32,8)
#pragma unroll
  for (int i = 0; i < 4; ++i)
    tile[ty + i * 8][tx] = src[(size_t)(r0 + ty + i * 8) * 1024 + c0 + tx];
  __syncthreads();
#pragma unroll
  for (int i = 0; i < 4; ++i)
    d[(size_t)(c0 + ty + i * 8) * 1024 + r0 + tx] = f2b(tile[tx][ty + i * 8]);
}

// ------------- V [B*S][D] bf16 -> Vt [B*D][S] bf16 (per-batch transpose) -------------
__global__ __launch_bounds__(256) void transpose_v(const u16* __restrict__ v,
                                                   u16* __restrict__ vtd) {
  __shared__ u16 tile[32][34];
  int b = blockIdx.z;
  int c0 = blockIdx.x * 32;   // d
  int s0 = blockIdx.y * 32;   // s
  int tx = threadIdx.x, ty = threadIdx.y;
#pragma unroll
  for (int i = 0; i < 4; ++i)
    tile[ty + i * 8][tx] = v[(size_t)(b * SS + s0 + ty + i * 8) * DD + c0 + tx];
  __syncthreads();
#pragma unroll
  for (int i = 0; i < 4; ++i)
    vtd[(size_t)(b * DD + c0 + ty + i * 8) * SS + s0 + tx] = tile[tx][ty + i * 8];
}

// ------------- GEMM: C[M][N] = A[M][K] @ Bt[N][K]^T, double-buffered prefetch -------------
template <typename OutT>
__global__ __launch_bounds__(256, 2)
void gemm_bt(const u16* __restrict__ A, const u16* __restrict__ Bt,
             OutT* __restrict__ C, const float* __restrict__ bias,
             float scale, int M, int N, int K) {
  const int tid = threadIdx.x;
  const int lane = tid & 63;
  const int w = tid >> 6;
  const int m0 = blockIdx.x * 128;
  const int n0 = blockIdx.y * 128;
  __shared__ u16 As[2][128 * 64];
  __shared__ u16 Bs[2][128 * 64];
  floatx4 acc[4][4];
#pragma unroll
  for (int i = 0; i < 4; ++i)
#pragma unroll
    for (int j = 0; j < 4; ++j) acc[i][j] = (floatx4){0.f, 0.f, 0.f, 0.f};

  const int wr = (w >> 1) * 64;
  const int wc = (w & 1) * 64;
  const int g = lane >> 4;
  const int lr = lane & 15;
  const size_t strideA = (size_t)K * 2;

  auto stage = [&](int k0, int buf) {
#pragma unroll
    for (int p = 0; p < 4; ++p) {
      int L = tid * 16 + p * 4096;
      int row = L >> 7;
      int cb = (L ^ ((row & 7) << 4)) & 127;
      gload_lds16((const char*)A + (size_t)(m0 + row) * strideA + k0 * 2 + cb,
                  (char*)As[buf] + p * 4096 + w * 1024);
      gload_lds16((const char*)Bt + (size_t)(n0 + row) * strideA + k0 * 2 + cb,
                  (char*)Bs[buf] + p * 4096 + w * 1024);
    }
  };

  const int nsteps = K >> 6;
  stage(0, 0);
  for (int t = 0; t < nsteps; ++t) {
    const int buf = t & 1;
    __syncthreads();                       // drains stage(t); guards buf reuse
    if (t + 1 < nsteps) stage((t + 1) << 6, buf ^ 1);
    const u16* as = As[buf];
    const u16* bs = Bs[buf];
#pragma unroll
    for (int ks = 0; ks < 2; ++ks) {
      short8 af[4], bf[4];
      const int c0 = ks * 32 + g * 8;
#pragma unroll
      for (int mi = 0; mi < 4; ++mi) {
        int row = wr + mi * 16 + lr;
        af[mi] = *(const short8*)(as + row * 64 + (c0 ^ ((row & 7) << 3)));
      }
#pragma unroll
      for (int ni = 0; ni < 4; ++ni) {
        int row = wc + ni * 16 + lr;
        bf[ni] = *(const short8*)(bs + row * 64 + (c0 ^ ((row & 7) << 3)));
      }
      __builtin_amdgcn_s_setprio(1);
#pragma unroll
      for (int mi = 0; mi < 4; ++mi)
#pragma unroll
        for (int ni = 0; ni < 4; ++ni)
          acc[mi][ni] = __builtin_amdgcn_mfma_f32_16x16x32_bf16(af[mi], bf[ni],
                                                                acc[mi][ni], 0, 0, 0);
      __builtin_amdgcn_s_setprio(0);
    }
  }
#pragma unroll
  for (int ni = 0; ni < 4; ++ni) {
    int col = n0 + wc + ni * 16 + lr;
    float bvv = bias ? bias[col] : 0.f;
#pragma unroll
    for (int mi = 0; mi < 4; ++mi) {
#pragma unroll
      for (int r = 0; r < 4; ++r) {
        int rowg = m0 + wr + mi * 16 + g * 4 + r;
        float val = (acc[mi][ni][r] + bvv) * scale;
        if constexpr (sizeof(OutT) == 4) C[(size_t)rowg * N + col] = val;
        else C[(size_t)rowg * N + col] = (OutT)f2b(val);
      }
    }
  }
}

// fused QKV wrapper (same dbuf structure): blockIdx.z selects segment (0=q,1=k,2=v)
__global__ __launch_bounds__(256, 2)
void gemm_qkv(const u16* __restrict__ A, const u16* __restrict__ Wt3,
              u16* __restrict__ Out3, const float* __restrict__ bq,
              const float* __restrict__ bv) {
  const int seg = blockIdx.z;
  const u16* Bt = Wt3 + (size_t)seg * 1024 * 1024;
  u16* C = Out3 + (size_t)seg * 4096 * 1024;
  const float* bias = (seg == 0) ? bq : (seg == 2) ? bv : nullptr;
  const float scale = (seg == 2) ? 1.0f : QKSCALE_E2;   // exp2-domain fold

  const int tid = threadIdx.x;
  const int lane = tid & 63;
  const int w = tid >> 6;
  const int m0 = blockIdx.x * 128;
  const int n0 = blockIdx.y * 128;
  __shared__ u16 As[2][128 * 64];
  __shared__ u16 Bs[2][128 * 64];
  floatx4 acc[4][4];
#pragma unroll
  for (int i = 0; i < 4; ++i)
#pragma unroll
    for (int j = 0; j < 4; ++j) acc[i][j] = (floatx4){0.f, 0.f, 0.f, 0.f};
  const int wr = (w >> 1) * 64;
  const int wc = (w & 1) * 64;
  const int g = lane >> 4;
  const int lr = lane & 15;

  auto stage = [&](int k0, int buf) {
#pragma unroll
    for (int p = 0; p < 4; ++p) {
      int L = tid * 16 + p * 4096;
      int row = L >> 7;
      int cb = (L ^ ((row & 7) << 4)) & 127;
      gload_lds16((const char*)A + (size_t)(m0 + row) * 2048 + k0 * 2 + cb,
                  (char*)As[buf] + p * 4096 + w * 1024);
      gload_lds16((const char*)Bt + (size_t)(n0 + row) * 2048 + k0 * 2 + cb,
                  (char*)Bs[buf] + p * 4096 + w * 1024);
    }
  };

  stage(0, 0);
  for (int t = 0; t < 16; ++t) {
    const int buf = t & 1;
    __syncthreads();
    if (t + 1 < 16) stage((t + 1) << 6, buf ^ 1);
    const u16* as = As[buf];
    const u16* bs = Bs[buf];
#pragma unroll
    for (int ks = 0; ks < 2; ++ks) {
      short8 af[4], bf[4];
      const int c0 = ks * 32 + g * 8;
#pragma unroll
      for (int mi = 0; mi < 4; ++mi) {
        int row = wr + mi * 16 + lr;
        af[mi] = *(const short8*)(as + row * 64 + (c0 ^ ((row & 7) << 3)));
      }
#pragma unroll
      for (int ni = 0; ni < 4; ++ni) {
        int row = wc + ni * 16 + lr;
        bf[ni] = *(const short8*)(bs + row * 64 + (c0 ^ ((row & 7) << 3)));
      }
      __builtin_amdgcn_s_setprio(1);
#pragma unroll
      for (int mi = 0; mi < 4; ++mi)
#pragma unroll
        for (int ni = 0; ni < 4; ++ni)
          acc[mi][ni] = __builtin_amdgcn_mfma_f32_16x16x32_bf16(af[mi], bf[ni],
                                                                acc[mi][ni], 0, 0, 0);
      __builtin_amdgcn_s_setprio(0);
    }
  }
#pragma unroll
  for (int ni = 0; ni < 4; ++ni) {
    int col = n0 + wc + ni * 16 + lr;
    float bvv = bias ? bias[col] : 0.f;
#pragma unroll
    for (int mi = 0; mi < 4; ++mi) {
#pragma unroll
      for (int r = 0; r < 4; ++r) {
        int rowg = m0 + wr + mi * 16 + g * 4 + r;
        C[(size_t)rowg * 1024 + col] = f2b((acc[mi][ni][r] + bvv) * scale);
      }
    }
  }
}

// ------------- flash attention: swapped-QK (S^T), single stream, 1 q-tile/block -------------
__device__ __forceinline__ void stream_softmax(floatx4 (&sa)[4], float& m, float& l,
                                               floatx4 (&acc)[4], u16* pl,
                                               bool diag, int wlr, int g, int lr) {
  if (diag) {
#pragma unroll
    for (int ct = 0; ct < 4; ++ct)
#pragma unroll
      for (int r = 0; r < 4; ++r)
        if (ct * 16 + g * 4 + r > wlr) sa[ct][r] += NEGBIG;
  }
  floatx4 v = vmax4(vmax4(sa[0], sa[1]), vmax4(sa[2], sa[3]));
  float mx = fmaxf(fmaxf(v[0], v[1]), fmaxf(v[2], v[3]));
  mx = fmaxf(mx, __shfl_xor(mx, 16, 64));
  mx = fmaxf(mx, __shfl_xor(mx, 32, 64));
  if (!__all(mx <= m + 8.f)) {
    float mn = fmaxf(m, mx);
    float al = ex2(m - mn);
    l *= al;
#pragma unroll
    for (int dt = 0; dt < 4; ++dt) acc[dt] *= al;
    m = mn;
  }
  floatx4 p[4];
#pragma unroll
  for (int ct = 0; ct < 4; ++ct)
#pragma unroll
    for (int r = 0; r < 4; ++r)
      p[ct][r] = ex2(sa[ct][r] - m);
  floatx4 s = (p[0] + p[1]) + (p[2] + p[3]);
  float rs = (s[0] + s[1]) + (s[2] + s[3]);
  rs += __shfl_xor(rs, 16, 64);
  rs += __shfl_xor(rs, 32, 64);
  l += rs;
#pragma unroll
  for (int ct = 0; ct < 4; ++ct) {
    ushort4v pk = { bconv(p[ct][0]), bconv(p[ct][1]),
                    bconv(p[ct][2]), bconv(p[ct][3]) };
    *(ushort4v*)((char*)pl + ((lr * 128 + ct * 32 + g * 8) ^ ((lr & 7) << 4))) = pk;
  }
}

__global__ __launch_bounds__(256, 4)
void flash_attn(const u16* __restrict__ q, const u16* __restrict__ k,
                const u16* __restrict__ vt, u16* __restrict__ o) {
  const int tid = threadIdx.x;
  const int lane = tid & 63;
  const int w = tid >> 6;
  const int g = lane >> 4;
  const int lr = lane & 15;
  // Dispatch-robust balanced mapping: x=XCD stream, kk position within stream.
  // qt = T((u+s)&3, v) with T(0)=v, T(1)=31-v, T(2)=16+v, T(3)=15-v.
  // Any co-resident set {s=0..3, u fixed} or {u=0..3, s fixed} sums nt to exactly 66.
  const int i = (int)blockIdx.x;      // 0..1023
  const int x = i & 7;
  const int kk = i >> 3;              // 0..127
  const int s = kk & 3;
  const int mI = kk >> 2;             // 0..31
  const int u = mI >> 3;
  const int v = mI & 7;
  const int gg = x * 4 + s;           // (b,h), 4 groups per XCD stream
  const int b = gg >> 4;
  const int h = gg & 15;
  const int a = (u + s) & 3;
  const int qt = (a == 0) ? v : (a == 1) ? (31 - v) : (a == 2) ? (16 + v) : (15 - v);
  const int row0 = qt * 64 + w * 16;
  const int wlr = w * 16 + lr;

  __shared__ u16 Ks[2][64 * 64];
  __shared__ u16 Vs[2][64 * 64];
  __shared__ u16 Pl[4][16 * 64];

  short8 qf[2];
  {
    const u16* qp = q + (size_t)(b * SS + row0 + lr) * DD + h * HD + g * 8;
    qf[0] = *(const short8*)qp;
    qf[1] = *(const short8*)(qp + 32);
  }
  floatx4 acc[4];
#pragma unroll
  for (int dt = 0; dt < 4; ++dt) acc[dt] = (floatx4){0.f, 0.f, 0.f, 0.f};
  float m = -1e30f, l = 0.f;

  const char* kbase = (const char*)(k + (size_t)(b * SS) * DD + h * HD);
  const char* vbase = (const char*)(vt + (size_t)((b * HH + h) * HD) * SS);
  const int nt = qt + 1;

  auto stage = [&](int t, int buf) {
    const int kvb = t * 64;
#pragma unroll
    for (int p = 0; p < 2; ++p) {
      int L = tid * 16 + p * 4096;
      int row = L >> 7;
      int cb = (L ^ ((row & 7) << 4)) & 127;
      gload_lds16(kbase + (size_t)(kvb + row) * (DD * 2) + cb,
                  (char*)Ks + buf * 8192 + p * 4096 + w * 1024);
      gload_lds16(vbase + (size_t)row * (SS * 2) + kvb * 2 + cb,
                  (char*)Vs + buf * 8192 + p * 4096 + w * 1024);
    }
  };

  stage(0, 0);
  int cur = 0;
  for (int t = 0; t < nt; ++t) {
    __syncthreads();
    if (t + 1 < nt) stage(t + 1, cur ^ 1);
    const u16* kc = Ks[cur];
    const u16* vc = Vs[cur];

    floatx4 sa[4];
#pragma unroll
    for (int ct = 0; ct < 4; ++ct) sa[ct] = (floatx4){0.f, 0.f, 0.f, 0.f};
    __builtin_amdgcn_s_setprio(1);
#pragma unroll
    for (int ks = 0; ks < 2; ++ks) {
      const int c0 = ks * 32 + g * 8;
#pragma unroll
      for (int ct = 0; ct < 4; ++ct) {
        int row = ct * 16 + lr;
        short8 kf = *(const short8*)(kc + row * 64 + (c0 ^ ((row & 7) << 3)));
        sa[ct] = __builtin_amdgcn_mfma_f32_16x16x32_bf16(kf, qf[ks], sa[ct], 0, 0, 0);
      }
    }
    __builtin_amdgcn_s_setprio(0);

    stream_softmax(sa, m, l, acc, Pl[w], t == qt, wlr, g, lr);

    __builtin_amdgcn_s_setprio(1);
#pragma unroll
    for (int ks = 0; ks < 2; ++ks) {
      const int c0 = ks * 32 + g * 8;
      int pby = (lr * 128 + ks * 64 + g * 16) ^ ((lr & 7) << 4);
      short8 pf = *(const short8*)((const char*)Pl[w] + pby);
#pragma unroll
      for (int dt = 0; dt < 4; ++dt) {
        int row = dt * 16 + lr;
        short8 vf = *(const short8*)(vc + row * 64 + (c0 ^ ((row & 7) << 3)));
        acc[dt] = __builtin_amdgcn_mfma_f32_16x16x32_bf16(vf, pf, acc[dt], 0, 0, 0);
      }
    }
    __builtin_amdgcn_s_setprio(0);
    cur ^= 1;
  }

  float inv = 1.0f / l;
#pragma unroll
  for (int dt = 0; dt < 4; ++dt) {
    ushort4v pa = { bconv(acc[dt][0] * inv), bconv(acc[dt][1] * inv),
                    bconv(acc[dt][2] * inv), bconv(acc[dt][3] * inv) };
    *(ushort4v*)(o + (size_t)(b * SS + row0 + lr) * DD + h * HD + dt * 16 + g * 4) = pa;
  }
}

extern "C" void kernel_launch(void* const* d_in, const int* in_sizes, int n_in,
                              void* d_out, int out_size, void* d_ws, size_t ws_size,
                              hipStream_t stream) {
  const float* x  = (const float*)d_in[0];
  // d_in[1] = mask: causal additive -1e9, replicated analytically in-kernel
  const float* Wq = (const float*)d_in[2];
  const float* bq = (const float*)d_in[3];
  const float* Wk = (const float*)d_in[4];
  const float* Wv = (const float*)d_in[5];
  const float* bv = (const float*)d_in[6];
  const float* Wo = (const float*)d_in[7];
  const float* bo = (const float*)d_in[8];
  float* out = (float*)d_out;

  char* ws = (char*)d_ws;
  u16* xb  = (u16*)(ws);                    // 8MB  x bf16 [4096][1024]
  u16* wt  = (u16*)(ws + (8u << 20));       // 8MB  Wq^T,Wk^T,Wv^T,Wo^T bf16
  u16* qkv = (u16*)(ws + (16u << 20));      // 24MB q,k,v bf16 [4096][1024] each
  u16* vb  = qkv + 2u * 4096 * 1024;
  u16* vtb = (u16*)(ws + (40u << 20));      // 8MB  v^T per batch [B*D][S]
  u16* ob  = (u16*)(ws + (48u << 20));      // 8MB  attn out bf16
  u16* wot = wt + 3u * 1024 * 1024;

  dim3 tb(32, 8);
  cvt_bf16x4<<<4096, 256, 0, stream>>>((const float4*)x, (ushort4v*)xb,
                                       (BB * SS * DD) / 4);
  transpose_w<<<dim3(32, 32, 4), tb, 0, stream>>>(Wq, Wk, Wv, Wo, wt);
  gemm_qkv<<<dim3(32, 8, 3), 256, 0, stream>>>(xb, wt, qkv, bq, bv);
  transpose_v<<<dim3(32, 64, 2), tb, 0, stream>>>(vb, vtb);
  flash_attn<<<1024, 256, 0, stream>>>(qkv, qkv + (size_t)4096 * 1024, vtb, ob);
  gemm_bt<float><<<dim3(32, 8), 256, 0, stream>>>(ob, wot, out, bo, 1.0f,
                                                  4096, 1024, 1024);
}

// Round 10
// 112.773 us; speedup vs baseline: 1.1863x; 1.0650x over previous
//
#include <hip/hip_runtime.h>
#include <hip/hip_bf16.h>

// Problem constants (Whisper-style MHA): B=2, S=2048, D=1024, H=16, hd=64
#define BB 2
#define SS 2048
#define DD 1024
#define HH 16
#define HD 64
#define QKSCALE 0.35355339059327373f   // 64^-0.25
// 64^-0.25 * sqrt(log2(e)) : folds exp->exp2 domain change into q,k projections
#define QKSCALE_E2 0.42466090144f
#define NEGBIG (-1e9f)

using u16 = unsigned short;
typedef __attribute__((ext_vector_type(8))) short short8;     // 8 bf16 = 4 VGPR
typedef __attribute__((ext_vector_type(4))) float floatx4;    // MFMA acc
typedef __attribute__((ext_vector_type(4))) unsigned short ushort4v;

#define GLOBAL_AS __attribute__((address_space(1)))
#define LDS_AS __attribute__((address_space(3)))

__device__ __forceinline__ u16 f2b(float f) {          // RNE f32->bf16
  union { float f; unsigned u; } v; v.f = f;
  return (u16)((v.u + 0x7fffu + ((v.u >> 16) & 1u)) >> 16);
}

__device__ __forceinline__ u16 bconv(float f) {        // via HW cvt (fuses to cvt_pk)
  union { __hip_bfloat16 h; u16 u; } cv;
  cv.h = __float2bfloat16(f);
  return cv.u;
}

__device__ __forceinline__ float ex2(float f) {        // raw v_exp_f32 (2^x)
  return __builtin_amdgcn_exp2f(f);
}

__device__ __forceinline__ floatx4 vmax4(floatx4 a, floatx4 b) {
  return (floatx4){fmaxf(a[0], b[0]), fmaxf(a[1], b[1]),
                   fmaxf(a[2], b[2]), fmaxf(a[3], b[3])};
}

__device__ __forceinline__ void gload_lds16(const void* g, void* l) {
  __builtin_amdgcn_global_load_lds((GLOBAL_AS void*)(g), (LDS_AS void*)(l), 16, 0, 0);
}

// ---------------- elementwise f32 -> bf16 ----------------
__global__ __launch_bounds__(256) void cvt_bf16x4(const float4* __restrict__ src,
                                                  ushort4v* __restrict__ dst, int n4) {
  int i = blockIdx.x * 256 + threadIdx.x;
  if (i >= n4) return;
  float4 f = src[i];
  ushort4v o = { f2b(f.x), f2b(f.y), f2b(f.z), f2b(f.w) };
  dst[i] = o;
}

// ------------- weight transpose+convert: W[K][N] f32 -> Wt[N][K] bf16 (4 weights) -------------
__global__ __launch_bounds__(256) void transpose_w(const float* __restrict__ s0,
                                                   const float* __restrict__ s1,
                                                   const float* __restrict__ s2,
                                                   const float* __restrict__ s3,
                                                   u16* __restrict__ dst) {
  __shared__ float tile[32][33];
  const float* src = (blockIdx.z == 0) ? s0 : (blockIdx.z == 1) ? s1
                   : (blockIdx.z == 2) ? s2 : s3;
  u16* d = dst + (size_t)blockIdx.z * 1024 * 1024;
  int c0 = blockIdx.x * 32, r0 = blockIdx.y * 32;
  int tx = threadIdx.x, ty = threadIdx.y;     // block (32,8)
#pragma unroll
  for (int i = 0; i < 4; ++i)
    tile[ty + i * 8][tx] = src[(size_t)(r0 + ty + i * 8) * 1024 + c0 + tx];
  __syncthreads();
#pragma unroll
  for (int i = 0; i < 4; ++i)
    d[(size_t)(c0 + ty + i * 8) * 1024 + r0 + tx] = f2b(tile[tx][ty + i * 8]);
}

// ------------- V [B*S][D] bf16 -> Vt [B*D][S] bf16 (per-batch transpose) -------------
__global__ __launch_bounds__(256) void transpose_v(const u16* __restrict__ v,
                                                   u16* __restrict__ vtd) {
  __shared__ u16 tile[32][34];
  int b = blockIdx.z;
  int c0 = blockIdx.x * 32;   // d
  int s0 = blockIdx.y * 32;   // s
  int tx = threadIdx.x, ty = threadIdx.y;
#pragma unroll
  for (int i = 0; i < 4; ++i)
    tile[ty + i * 8][tx] = v[(size_t)(b * SS + s0 + ty + i * 8) * DD + c0 + tx];
  __syncthreads();
#pragma unroll
  for (int i = 0; i < 4; ++i)
    vtd[(size_t)(b * DD + c0 + ty + i * 8) * SS + s0 + tx] = tile[tx][ty + i * 8];
}

// ------------- out-proj GEMM: 64x128 tile, BK=64, dbuf prefetch -------------
// grid 64x8 = 512 blocks; LDS 48KB -> 3 blocks/CU capacity -> uniform 2/CU resident.
// 4 waves as 2x2 over (64,128): wave sub-tile 32x64, acc[2][4].
template <typename OutT>
__global__ __launch_bounds__(256, 3)
void gemm_bt(const u16* __restrict__ A, const u16* __restrict__ Bt,
             OutT* __restrict__ C, const float* __restrict__ bias,
             float scale, int M, int N, int K) {
  const int tid = threadIdx.x;
  const int lane = tid & 63;
  const int w = tid >> 6;
  const int m0 = blockIdx.x * 64;
  const int n0 = blockIdx.y * 128;
  __shared__ u16 As[2][64 * 64];     // 8KB per buf
  __shared__ u16 Bs[2][128 * 64];    // 16KB per buf
  floatx4 acc[2][4];
#pragma unroll
  for (int i = 0; i < 2; ++i)
#pragma unroll
    for (int j = 0; j < 4; ++j) acc[i][j] = (floatx4){0.f, 0.f, 0.f, 0.f};

  const int wr = (w >> 1) * 32;
  const int wc = (w & 1) * 64;
  const int g = lane >> 4;
  const int lr = lane & 15;
  const size_t strideA = (size_t)K * 2;

  auto stage = [&](int k0, int buf) {
#pragma unroll
    for (int p = 0; p < 2; ++p) {    // A: 8KB
      int L = tid * 16 + p * 4096;
      int row = L >> 7;
      int cb = (L ^ ((row & 7) << 4)) & 127;
      gload_lds16((const char*)A + (size_t)(m0 + row) * strideA + k0 * 2 + cb,
                  (char*)As[buf] + p * 4096 + w * 1024);
    }
#pragma unroll
    for (int p = 0; p < 4; ++p) {    // B: 16KB
      int L = tid * 16 + p * 4096;
      int row = L >> 7;
      int cb = (L ^ ((row & 7) << 4)) & 127;
      gload_lds16((const char*)Bt + (size_t)(n0 + row) * strideA + k0 * 2 + cb,
                  (char*)Bs[buf] + p * 4096 + w * 1024);
    }
  };

  const int nsteps = K >> 6;
  stage(0, 0);
  for (int t = 0; t < nsteps; ++t) {
    const int buf = t & 1;
    __syncthreads();                       // drains stage(t); guards buf reuse
    if (t + 1 < nsteps) stage((t + 1) << 6, buf ^ 1);
    const u16* as = As[buf];
    const u16* bs = Bs[buf];
#pragma unroll
    for (int ks = 0; ks < 2; ++ks) {
      short8 af[2], bf[4];
      const int c0 = ks * 32 + g * 8;
#pragma unroll
      for (int mi = 0; mi < 2; ++mi) {
        int row = wr + mi * 16 + lr;
        af[mi] = *(const short8*)(as + row * 64 + (c0 ^ ((row & 7) << 3)));
      }
#pragma unroll
      for (int ni = 0; ni < 4; ++ni) {
        int row = wc + ni * 16 + lr;
        bf[ni] = *(const short8*)(bs + row * 64 + (c0 ^ ((row & 7) << 3)));
      }
      __builtin_amdgcn_s_setprio(1);
#pragma unroll
      for (int mi = 0; mi < 2; ++mi)
#pragma unroll
        for (int ni = 0; ni < 4; ++ni)
          acc[mi][ni] = __builtin_amdgcn_mfma_f32_16x16x32_bf16(af[mi], bf[ni],
                                                                acc[mi][ni], 0, 0, 0);
      __builtin_amdgcn_s_setprio(0);
    }
  }
#pragma unroll
  for (int ni = 0; ni < 4; ++ni) {
    int col = n0 + wc + ni * 16 + lr;
    float bvv = bias ? bias[col] : 0.f;
#pragma unroll
    for (int mi = 0; mi < 2; ++mi) {
#pragma unroll
      for (int r = 0; r < 4; ++r) {
        int rowg = m0 + wr + mi * 16 + g * 4 + r;
        float val = (acc[mi][ni][r] + bvv) * scale;
        if constexpr (sizeof(OutT) == 4) C[(size_t)rowg * N + col] = val;
        else C[(size_t)rowg * N + col] = (OutT)f2b(val);
      }
    }
  }
}

// ------------- fused QKV GEMM: 128x128 tile, BK=32 dbuf -> 32KB LDS, 3 blocks/CU -------------
// grid 32x8x3 = 768 = exactly 3/CU in ONE residency round (was 1.5 rounds at BK=64).
// BK=32 rows are 64B; pair logical rows r into 128B LDS rows:
//   phys(r, cb) = (r>>1)*128 + ((((r&1)<<6) | cb) ^ (((r>>1)&7)<<4))
// -> frag reads hit all eight 16B slots of each 128B span, 2 lanes/slot (proven-free pattern).
__global__ __launch_bounds__(256, 4)
void gemm_qkv(const u16* __restrict__ A, const u16* __restrict__ Wt3,
              u16* __restrict__ Out3, const float* __restrict__ bq,
              const float* __restrict__ bv) {
  const int seg = blockIdx.z;
  const u16* Bt = Wt3 + (size_t)seg * 1024 * 1024;
  u16* C = Out3 + (size_t)seg * 4096 * 1024;
  const float* bias = (seg == 0) ? bq : (seg == 2) ? bv : nullptr;
  const float scale = (seg == 2) ? 1.0f : QKSCALE_E2;   // exp2-domain fold

  const int tid = threadIdx.x;
  const int lane = tid & 63;
  const int w = tid >> 6;
  const int m0 = blockIdx.x * 128;
  const int n0 = blockIdx.y * 128;
  __shared__ u16 As[2][64 * 64];   // 8KB per buf (128 logical rows x 32 cols, row-paired)
  __shared__ u16 Bs[2][64 * 64];
  floatx4 acc[4][4];
#pragma unroll
  for (int i = 0; i < 4; ++i)
#pragma unroll
    for (int j = 0; j < 4; ++j) acc[i][j] = (floatx4){0.f, 0.f, 0.f, 0.f};
  const int wr = (w >> 1) * 64;
  const int wc = (w & 1) * 64;
  const int g = lane >> 4;
  const int lr = lane & 15;

  auto stage = [&](int k0, int buf) {
#pragma unroll
    for (int p = 0; p < 2; ++p) {
      int L = tid * 16 + p * 4096;
      int lrow = L >> 7;                      // 0..63 LDS row (128B)
      int un = (L & 127) ^ ((lrow & 7) << 4); // un-swizzled intra-row byte
      int r = lrow * 2 + (un >> 6);           // logical row 0..127
      int cb = un & 63;                       // k-byte 0..63 (32 elems)
      gload_lds16((const char*)A + (size_t)(m0 + r) * 2048 + k0 * 2 + cb,
                  (char*)As[buf] + p * 4096 + w * 1024);
      gload_lds16((const char*)Bt + (size_t)(n0 + r) * 2048 + k0 * 2 + cb,
                  (char*)Bs[buf] + p * 4096 + w * 1024);
    }
  };

  stage(0, 0);
  for (int t = 0; t < 32; ++t) {             // 32 K-steps of 32
    const int buf = t & 1;
    __syncthreads();                         // drains stage(t); guards buf reuse
    if (t + 1 < 32) stage((t + 1) << 5, buf ^ 1);
    const u16* as = As[buf];
    const u16* bs = Bs[buf];
    short8 af[4], bf[4];
#pragma unroll
    for (int mi = 0; mi < 4; ++mi) {
      int r = wr + mi * 16 + lr;
      af[mi] = *(const short8*)((const char*)as +
               ((r >> 1) * 128 + ((((r & 1) << 6) | (g * 16)) ^ (((r >> 1) & 7) << 4))));
    }
#pragma unroll
    for (int ni = 0; ni < 4; ++ni) {
      int r = wc + ni * 16 + lr;
      bf[ni] = *(const short8*)((const char*)bs +
               ((r >> 1) * 128 + ((((r & 1) << 6) | (g * 16)) ^ (((r >> 1) & 7) << 4))));
    }
    __builtin_amdgcn_s_setprio(1);
#pragma unroll
    for (int mi = 0; mi < 4; ++mi)
#pragma unroll
      for (int ni = 0; ni < 4; ++ni)
        acc[mi][ni] = __builtin_amdgcn_mfma_f32_16x16x32_bf16(af[mi], bf[ni],
                                                              acc[mi][ni], 0, 0, 0);
    __builtin_amdgcn_s_setprio(0);
  }
#pragma unroll
  for (int ni = 0; ni < 4; ++ni) {
    int col = n0 + wc + ni * 16 + lr;
    float bvv = bias ? bias[col] : 0.f;
#pragma unroll
    for (int mi = 0; mi < 4; ++mi) {
#pragma unroll
      for (int r = 0; r < 4; ++r) {
        int rowg = m0 + wr + mi * 16 + g * 4 + r;
        C[(size_t)rowg * 1024 + col] = f2b((acc[mi][ni][r] + bvv) * scale);
      }
    }
  }
}

// ------------- flash attention: swapped-QK (S^T), single stream, 1 q-tile/block -------------
__device__ __forceinline__ void stream_softmax(floatx4 (&sa)[4], float& m, float& l,
                                               floatx4 (&acc)[4], u16* pl,
                                               bool diag, int wlr, int g, int lr) {
  if (diag) {
#pragma unroll
    for (int ct = 0; ct < 4; ++ct)
#pragma unroll
      for (int r = 0; r < 4; ++r)
        if (ct * 16 + g * 4 + r > wlr) sa[ct][r] += NEGBIG;
  }
  floatx4 v = vmax4(vmax4(sa[0], sa[1]), vmax4(sa[2], sa[3]));
  float mx = fmaxf(fmaxf(v[0], v[1]), fmaxf(v[2], v[3]));
  mx = fmaxf(mx, __shfl_xor(mx, 16, 64));
  mx = fmaxf(mx, __shfl_xor(mx, 32, 64));
  if (!__all(mx <= m + 8.f)) {
    float mn = fmaxf(m, mx);
    float al = ex2(m - mn);
    l *= al;
#pragma unroll
    for (int dt = 0; dt < 4; ++dt) acc[dt] *= al;
    m = mn;
  }
  floatx4 p[4];
#pragma unroll
  for (int ct = 0; ct < 4; ++ct)
#pragma unroll
    for (int r = 0; r < 4; ++r)
      p[ct][r] = ex2(sa[ct][r] - m);
  floatx4 s = (p[0] + p[1]) + (p[2] + p[3]);
  float rs = (s[0] + s[1]) + (s[2] + s[3]);
  rs += __shfl_xor(rs, 16, 64);
  rs += __shfl_xor(rs, 32, 64);
  l += rs;
#pragma unroll
  for (int ct = 0; ct < 4; ++ct) {
    ushort4v pk = { bconv(p[ct][0]), bconv(p[ct][1]),
                    bconv(p[ct][2]), bconv(p[ct][3]) };
    *(ushort4v*)((char*)pl + ((lr * 128 + ct * 32 + g * 8) ^ ((lr & 7) << 4))) = pk;
  }
}

__global__ __launch_bounds__(256, 4)
void flash_attn(const u16* __restrict__ q, const u16* __restrict__ k,
                const u16* __restrict__ vt, u16* __restrict__ o) {
  const int tid = threadIdx.x;
  const int lane = tid & 63;
  const int w = tid >> 6;
  const int g = lane >> 4;
  const int lr = lane & 15;
  const int i = (int)blockIdx.x;      // 0..1023
  const int x = i & 7;
  const int kk = i >> 3;              // 0..127
  const int s = kk & 3;
  const int mI = kk >> 2;             // 0..31
  const int u = mI >> 3;
  const int v = mI & 7;
  const int gg = x * 4 + s;           // (b,h), 4 groups per XCD stream
  const int b = gg >> 4;
  const int h = gg & 15;
  const int a = (u + s) & 3;
  const int qt = (a == 0) ? v : (a == 1) ? (31 - v) : (a == 2) ? (16 + v) : (15 - v);
  const int row0 = qt * 64 + w * 16;
  const int wlr = w * 16 + lr;

  __shared__ u16 Ks[2][64 * 64];
  __shared__ u16 Vs[2][64 * 64];
  __shared__ u16 Pl[4][16 * 64];

  short8 qf[2];
  {
    const u16* qp = q + (size_t)(b * SS + row0 + lr) * DD + h * HD + g * 8;
    qf[0] = *(const short8*)qp;
    qf[1] = *(const short8*)(qp + 32);
  }
  floatx4 acc[4];
#pragma unroll
  for (int dt = 0; dt < 4; ++dt) acc[dt] = (floatx4){0.f, 0.f, 0.f, 0.f};
  float m = -1e30f, l = 0.f;

  const char* kbase = (const char*)(k + (size_t)(b * SS) * DD + h * HD);
  const char* vbase = (const char*)(vt + (size_t)((b * HH + h) * HD) * SS);
  const int nt = qt + 1;

  auto stage = [&](int t, int buf) {
    const int kvb = t * 64;
#pragma unroll
    for (int p = 0; p < 2; ++p) {
      int L = tid * 16 + p * 4096;
      int row = L >> 7;
      int cb = (L ^ ((row & 7) << 4)) & 127;
      gload_lds16(kbase + (size_t)(kvb + row) * (DD * 2) + cb,
                  (char*)Ks + buf * 8192 + p * 4096 + w * 1024);
      gload_lds16(vbase + (size_t)row * (SS * 2) + kvb * 2 + cb,
                  (char*)Vs + buf * 8192 + p * 4096 + w * 1024);
    }
  };

  stage(0, 0);
  int cur = 0;
  for (int t = 0; t < nt; ++t) {
    __syncthreads();
    if (t + 1 < nt) stage(t + 1, cur ^ 1);
    const u16* kc = Ks[cur];
    const u16* vc = Vs[cur];

    floatx4 sa[4];
#pragma unroll
    for (int ct = 0; ct < 4; ++ct) sa[ct] = (floatx4){0.f, 0.f, 0.f, 0.f};
    __builtin_amdgcn_s_setprio(1);
#pragma unroll
    for (int ks = 0; ks < 2; ++ks) {
      const int c0 = ks * 32 + g * 8;
#pragma unroll
      for (int ct = 0; ct < 4; ++ct) {
        int row = ct * 16 + lr;
        short8 kf = *(const short8*)(kc + row * 64 + (c0 ^ ((row & 7) << 3)));
        sa[ct] = __builtin_amdgcn_mfma_f32_16x16x32_bf16(kf, qf[ks], sa[ct], 0, 0, 0);
      }
    }
    __builtin_amdgcn_s_setprio(0);

    stream_softmax(sa, m, l, acc, Pl[w], t == qt, wlr, g, lr);

    __builtin_amdgcn_s_setprio(1);
#pragma unroll
    for (int ks = 0; ks < 2; ++ks) {
      const int c0 = ks * 32 + g * 8;
      int pby = (lr * 128 + ks * 64 + g * 16) ^ ((lr & 7) << 4);
      short8 pf = *(const short8*)((const char*)Pl[w] + pby);
#pragma unroll
      for (int dt = 0; dt < 4; ++dt) {
        int row = dt * 16 + lr;
        short8 vf = *(const short8*)(vc + row * 64 + (c0 ^ ((row & 7) << 3)));
        acc[dt] = __builtin_amdgcn_mfma_f32_16x16x32_bf16(vf, pf, acc[dt], 0, 0, 0);
      }
    }
    __builtin_amdgcn_s_setprio(0);
    cur ^= 1;
  }

  float inv = 1.0f / l;
#pragma unroll
  for (int dt = 0; dt < 4; ++dt) {
    ushort4v pa = { bconv(acc[dt][0] * inv), bconv(acc[dt][1] * inv),
                    bconv(acc[dt][2] * inv), bconv(acc[dt][3] * inv) };
    *(ushort4v*)(o + (size_t)(b * SS + row0 + lr) * DD + h * HD + dt * 16 + g * 4) = pa;
  }
}

extern "C" void kernel_launch(void* const* d_in, const int* in_sizes, int n_in,
                              void* d_out, int out_size, void* d_ws, size_t ws_size,
                              hipStream_t stream) {
  const float* x  = (const float*)d_in[0];
  // d_in[1] = mask: causal additive -1e9, replicated analytically in-kernel
  const float* Wq = (const float*)d_in[2];
  const float* bq = (const float*)d_in[3];
  const float* Wk = (const float*)d_in[4];
  const float* Wv = (const float*)d_in[5];
  const float* bv = (const float*)d_in[6];
  const float* Wo = (const float*)d_in[7];
  const float* bo = (const float*)d_in[8];
  float* out = (float*)d_out;

  char* ws = (char*)d_ws;
  u16* xb  = (u16*)(ws);                    // 8MB  x bf16 [4096][1024]
  u16* wt  = (u16*)(ws + (8u << 20));       // 8MB  Wq^T,Wk^T,Wv^T,Wo^T bf16
  u16* qkv = (u16*)(ws + (16u << 20));      // 24MB q,k,v bf16 [4096][1024] each
  u16* vb  = qkv + 2u * 4096 * 1024;
  u16* vtb = (u16*)(ws + (40u << 20));      // 8MB  v^T per batch [B*D][S]
  u16* ob  = (u16*)(ws + (48u << 20));      // 8MB  attn out bf16
  u16* wot = wt + 3u * 1024 * 1024;

  dim3 tb(32, 8);
  cvt_bf16x4<<<4096, 256, 0, stream>>>((const float4*)x, (ushort4v*)xb,
                                       (BB * SS * DD) / 4);
  transpose_w<<<dim3(32, 32, 4), tb, 0, stream>>>(Wq, Wk, Wv, Wo, wt);
  gemm_qkv<<<dim3(32, 8, 3), 256, 0, stream>>>(xb, wt, qkv, bq, bv);
  transpose_v<<<dim3(32, 64, 2), tb, 0, stream>>>(vb, vtb);
  flash_attn<<<1024, 256, 0, stream>>>(qkv, qkv + (size_t)4096 * 1024, vtb, ob);
  gemm_bt<float><<<dim3(64, 8), 256, 0, stream>>>(ob, wot, out, bo, 1.0f,
                                                  4096, 1024, 1024);
}